// Round 2
// baseline (2862.937 us; speedup 1.0000x reference)
//
#include <hip/hip_runtime.h>

typedef __attribute__((ext_vector_type(8))) short short8;
typedef __attribute__((ext_vector_type(4))) float f32x4;

#define LNE 1e-5f

__device__ __forceinline__ unsigned short f2bf(float f) {
  union { float f; unsigned int u; } v; v.f = f;
  unsigned int r = v.u + 0x7fffu + ((v.u >> 16) & 1u);
  return (unsigned short)(r >> 16);
}
__device__ __forceinline__ float bf2f(unsigned short s) {
  union { unsigned int u; float f; } v; v.u = ((unsigned int)s) << 16;
  return v.f;
}
__device__ __forceinline__ unsigned int pk2(float a, float b) {
  return (unsigned int)f2bf(a) | ((unsigned int)f2bf(b) << 16);
}

// ---- weight prep: fp32 -> bf16, transposed to [n][k] ----
// ws layout (ushort elems):
//   wqkvT [1152][384]  rows: mat*384 + head*48 + e       (0 .. 442368)
//   woT   [384][384]   woT[n][d] = wo[d][n]              (442368 .. 589824)
//   w1T   [1536][384]  w1T[n][d] = w1[d][n]              (589824 .. 1179648)
//   w2T   [384][1536]  w2T[n][c] = w2[c][n]              (1179648 .. 1769472)
__global__ void prep_kernel(const float* __restrict__ wq, const float* __restrict__ wk,
                            const float* __restrict__ wv, const float* __restrict__ wo,
                            const float* __restrict__ w1, const float* __restrict__ w2,
                            unsigned short* __restrict__ ws) {
  int idx = blockIdx.x * 256 + threadIdx.x;
  if (idx < 442368) {
    int n = idx / 384, d = idx % 384;
    int mat = n / 384, rem = n % 384, head = rem / 48, e = rem % 48;
    const float* w = (mat == 0) ? wq : ((mat == 1) ? wk : wv);
    ws[idx] = f2bf(w[(head * 384 + d) * 48 + e]);
  } else if (idx < 589824) {
    int j = idx - 442368; int n = j / 384, d = j % 384;
    ws[idx] = f2bf(wo[d * 384 + n]);
  } else if (idx < 1179648) {
    int j = idx - 589824; int n = j / 384, d = j % 384;
    ws[idx] = f2bf(w1[d * 1536 + n]);
  } else if (idx < 1769472) {
    int j = idx - 1179648; int n = j / 1536, c = j % 1536;
    ws[idx] = f2bf(w2[c * 384 + n]);
  }
}

// ---- fused transformer block: one 512-thread workgroup per batch ----
// 8 waves = 2 waves/SIMD at 1 block/CU (LDS 146.5 KB).
__global__ __launch_bounds__(512, 1) void block_fused(
    const float* __restrict__ x,
    const float* __restrict__ bq, const float* __restrict__ bk, const float* __restrict__ bv,
    const float* __restrict__ bo, const float* __restrict__ b1, const float* __restrict__ b2,
    const float* __restrict__ g1, const float* __restrict__ be1,
    const float* __restrict__ g2, const float* __restrict__ be2,
    const unsigned short* __restrict__ wt,
    float* __restrict__ out) {
  // strides 392/136/72: row byte-stride ≡ 16 mod 128 -> 2-way bank alias only (free), 16B-aligned
  __shared__ unsigned short sH[64 * 392];   // h after LN1; h2 after LN2
  __shared__ unsigned short sA[64 * 392];   // attn concat; reused as U (FFN1 chunk)
  __shared__ unsigned short sQ[64 * 136];   // q for 2 heads (e padded to 64); P after softmax
  __shared__ unsigned short sK[64 * 136];   // k for 2 heads (e padded to 64)
  __shared__ unsigned short sVT[96 * 72];   // v^T [hh*48+e][s] for 2 heads
  __shared__ float sRed[2][64][2];          // LN2 cross-wave (sum, sumsq) halves

  const int tid  = threadIdx.x;
  const int wv   = tid >> 6, lane = tid & 63;
  const int quad = lane >> 4, l15 = lane & 15;
  const int mt   = wv & 3;        // row-tile (t dimension) this wave owns
  const int grp  = wv >> 2;       // column-half / head-of-pair selector
  const int b = blockIdx.x;

  const unsigned short* wqkvT = wt;
  const unsigned short* woT   = wt + 442368;
  const unsigned short* w1T   = wt + 589824;
  const unsigned short* w2T   = wt + 1179648;

  // ================= Phase 0: LN1, x -> sH (bf16) =================
  {
    const int r = tid >> 3, sub = tid & 7;     // 8 threads per row, 48 cols each
    const float* xr = x + ((size_t)b * 64 + r) * 384 + sub * 48;
    float s = 0.f, s2 = 0.f;
#pragma unroll
    for (int i = 0; i < 12; ++i) {
      float4 v = ((const float4*)xr)[i];
      s  += v.x + v.y + v.z + v.w;
      s2 += v.x * v.x + v.y * v.y + v.z * v.z + v.w * v.w;
    }
    s  += __shfl_xor(s, 1);  s  += __shfl_xor(s, 2);  s  += __shfl_xor(s, 4);
    s2 += __shfl_xor(s2, 1); s2 += __shfl_xor(s2, 2); s2 += __shfl_xor(s2, 4);
    float mu = s * (1.f / 384.f);
    float rstd = rsqrtf(s2 * (1.f / 384.f) - mu * mu + LNE);
#pragma unroll
    for (int i = 0; i < 12; ++i) {
      float4 v = ((const float4*)xr)[i];
      int c = sub * 48 + i * 4;
      float4 gv = *(const float4*)&g1[c];
      float4 bv_ = *(const float4*)&be1[c];
      float h0 = (v.x - mu) * rstd * gv.x + bv_.x;
      float h1 = (v.y - mu) * rstd * gv.y + bv_.y;
      float h2 = (v.z - mu) * rstd * gv.z + bv_.z;
      float h3 = (v.w - mu) * rstd * gv.w + bv_.w;
      *(uint2*)&sH[r * 392 + c] = make_uint2(pk2(h0, h1), pk2(h2, h3));
    }
  }
  __syncthreads();

  // ================= Phase 1: attention, 2 heads per iteration =================
#pragma unroll 1
  for (int p = 0; p < 4; ++p) {
    {   // zero-pad q/k cols 48..63 of each head section (K=64 MFMA padding)
      int rr = tid >> 3, kk = (tid & 7) * 2;
      *(unsigned int*)&sQ[rr * 136 + 48 + kk] = 0u;
      *(unsigned int*)&sQ[rr * 136 + 112 + kk] = 0u;
      *(unsigned int*)&sK[rr * 136 + 48 + kk] = 0u;
      *(unsigned int*)&sK[rr * 136 + 112 + kk] = 0u;
    }
    // --- QKV projections for both heads: wave = (row-tile mt) x (9 col-tiles) ---
    {
      f32x4 acc[9];
#pragma unroll
      for (int j = 0; j < 9; ++j) acc[j] = (f32x4){0.f, 0.f, 0.f, 0.f};
      const unsigned short* ap = sH + (mt * 16 + l15) * 392 + quad * 8;
      const unsigned short* bp[9];
#pragma unroll
      for (int j = 0; j < 9; ++j) {
        int ct = grp * 9 + j;                 // 0..17
        int mat = ct / 6, rem = ct % 6, hh = rem / 3, et = rem % 3;
        int head = 2 * p + hh;
        bp[j] = wqkvT + (size_t)((mat * 8 + head) * 48 + et * 16 + l15) * 384 + quad * 8;
      }
#pragma unroll 2
      for (int k = 0; k < 12; ++k) {
        short8 a = *(const short8*)(ap + k * 32);
#pragma unroll
        for (int j = 0; j < 9; ++j)
          acc[j] = __builtin_amdgcn_mfma_f32_16x16x32_bf16(a, *(const short8*)(bp[j] + k * 32), acc[j], 0, 0, 0);
      }
#pragma unroll
      for (int j = 0; j < 9; ++j) {
        int ct = grp * 9 + j;
        int mat = ct / 6, rem = ct % 6, hh = rem / 3, et = rem % 3;
        int head = 2 * p + hh;
        const float* bias = (mat == 0) ? bq : ((mat == 1) ? bk : bv);
        float bsv = bias[head * 48 + et * 16 + l15];
        if (mat == 2) {   // v -> sVT[hh*48+e][s], contiguous in s -> b64 pack
          *(uint2*)&sVT[(hh * 48 + et * 16 + l15) * 72 + mt * 16 + quad * 4] =
              make_uint2(pk2(acc[j][0] + bsv, acc[j][1] + bsv), pk2(acc[j][2] + bsv, acc[j][3] + bsv));
        } else {          // q/k -> [t][hh*64+e], scalar scatter
          unsigned short* dst = (mat == 0) ? sQ : sK;
#pragma unroll
          for (int i = 0; i < 4; ++i)
            dst[(mt * 16 + quad * 4 + i) * 136 + hh * 64 + et * 16 + l15] = f2bf(acc[j][i] + bsv);
        }
      }
    }
    __syncthreads();

    // --- S = q k^T : wave = (head grp) x (q-row-tile mt); causal softmax in-register ---
    {
      f32x4 sc[4];
#pragma unroll
      for (int ts = 0; ts < 4; ++ts) {
        f32x4 acc = {0.f, 0.f, 0.f, 0.f};
#pragma unroll
        for (int k = 0; k < 2; ++k) {
          short8 a  = *(const short8*)&sQ[(mt * 16 + l15) * 136 + grp * 64 + k * 32 + quad * 8];
          short8 bb = *(const short8*)&sK[(ts * 16 + l15) * 136 + grp * 64 + k * 32 + quad * 8];
          acc = __builtin_amdgcn_mfma_f32_16x16x32_bf16(a, bb, acc, 0, 0, 0);
        }
        sc[ts] = acc;
      }
      const float scale = 0.14433756729740645f;  // 48^-0.5
#pragma unroll
      for (int i = 0; i < 4; ++i) {
        int t = mt * 16 + quad * 4 + i;
        float vvv[4];
#pragma unroll
        for (int ts = 0; ts < 4; ++ts) {
          int s_ = ts * 16 + l15;
          float v = sc[ts][i] * scale;
          vvv[ts] = (s_ <= t) ? v : -INFINITY;
        }
        float mx = fmaxf(fmaxf(vvv[0], vvv[1]), fmaxf(vvv[2], vvv[3]));
        mx = fmaxf(mx, __shfl_xor(mx, 1)); mx = fmaxf(mx, __shfl_xor(mx, 2));
        mx = fmaxf(mx, __shfl_xor(mx, 4)); mx = fmaxf(mx, __shfl_xor(mx, 8));
        float sum = 0.f;
#pragma unroll
        for (int ts = 0; ts < 4; ++ts) { vvv[ts] = __expf(vvv[ts] - mx); sum += vvv[ts]; }
        sum += __shfl_xor(sum, 1); sum += __shfl_xor(sum, 2);
        sum += __shfl_xor(sum, 4); sum += __shfl_xor(sum, 8);
        float inv = 1.f / sum;
#pragma unroll
        for (int ts = 0; ts < 4; ++ts)           // P -> sQ[t][grp*64+s] (q is dead)
          sQ[t * 136 + grp * 64 + ts * 16 + l15] = f2bf(vvv[ts] * inv);
      }
    }
    __syncthreads();

    // --- attn^T = V^T P^T ; wave = (head grp) x (t-tile mt) ---
    {
      int head = 2 * p + grp;
#pragma unroll
      for (int et = 0; et < 3; ++et) {
        f32x4 acc = {0.f, 0.f, 0.f, 0.f};
#pragma unroll
        for (int k = 0; k < 2; ++k) {
          short8 a  = *(const short8*)&sVT[(grp * 48 + et * 16 + l15) * 72 + k * 32 + quad * 8];
          short8 bb = *(const short8*)&sQ[(mt * 16 + l15) * 136 + grp * 64 + k * 32 + quad * 8];
          acc = __builtin_amdgcn_mfma_f32_16x16x32_bf16(a, bb, acc, 0, 0, 0);
        }
        *(uint2*)&sA[(mt * 16 + l15) * 392 + head * 48 + et * 16 + quad * 4] =
            make_uint2(pk2(acc[0], acc[1]), pk2(acc[2], acc[3]));
      }
    }
    __syncthreads();
  }

  // ================= Phase 2: out-proj + residual + LN2 =================
  {
    f32x4 oacc[12];
#pragma unroll
    for (int j = 0; j < 12; ++j) oacc[j] = (f32x4){0.f, 0.f, 0.f, 0.f};
    const unsigned short* ap = sA + (mt * 16 + l15) * 392 + quad * 8;
    const unsigned short* wop = woT + (size_t)(grp * 192 + l15) * 384 + quad * 8;
#pragma unroll 2
    for (int k = 0; k < 12; ++k) {
      short8 a = *(const short8*)(ap + k * 32);
#pragma unroll
      for (int j = 0; j < 12; ++j)
        oacc[j] = __builtin_amdgcn_mfma_f32_16x16x32_bf16(a, *(const short8*)(wop + j * 6144 + k * 32), oacc[j], 0, 0, 0);
    }
    // r = h + attn@wo + bo ; per-row partial sums for LN2
    float s_[4] = {0.f, 0.f, 0.f, 0.f}, s2_[4] = {0.f, 0.f, 0.f, 0.f};
#pragma unroll
    for (int j = 0; j < 12; ++j) {
      int n = grp * 192 + j * 16 + l15;
      float bov = bo[n];
#pragma unroll
      for (int i = 0; i < 4; ++i) {
        float hv = bf2f(sH[(mt * 16 + quad * 4 + i) * 392 + n]);
        float r = oacc[j][i] + bov + hv;
        oacc[j][i] = r;
        s_[i] += r; s2_[i] += r * r;
      }
    }
#pragma unroll
    for (int i = 0; i < 4; ++i) {
      s_[i]  += __shfl_xor(s_[i], 1);  s_[i]  += __shfl_xor(s_[i], 2);
      s_[i]  += __shfl_xor(s_[i], 4);  s_[i]  += __shfl_xor(s_[i], 8);
      s2_[i] += __shfl_xor(s2_[i], 1); s2_[i] += __shfl_xor(s2_[i], 2);
      s2_[i] += __shfl_xor(s2_[i], 4); s2_[i] += __shfl_xor(s2_[i], 8);
    }
    if (l15 == 0) {
#pragma unroll
      for (int i = 0; i < 4; ++i) {
        int t = mt * 16 + quad * 4 + i;
        sRed[grp][t][0] = s_[i];
        sRed[grp][t][1] = s2_[i];
      }
    }
    __syncthreads();
    float mu_[4], rs_[4];
#pragma unroll
    for (int i = 0; i < 4; ++i) {
      int t = mt * 16 + quad * 4 + i;
      float ssum = sRed[0][t][0] + sRed[1][t][0];
      float ssq  = sRed[0][t][1] + sRed[1][t][1];
      float mu = ssum * (1.f / 384.f);
      mu_[i] = mu;
      rs_[i] = rsqrtf(ssq * (1.f / 384.f) - mu * mu + LNE);
    }
#pragma unroll
    for (int j = 0; j < 12; ++j) {
      int n = grp * 192 + j * 16 + l15;
      float gv = g2[n], bev = be2[n];
#pragma unroll
      for (int i = 0; i < 4; ++i) {
        int t = mt * 16 + quad * 4 + i;
        sH[t * 392 + n] = f2bf((oacc[j][i] - mu_[i]) * rs_[i] * gv + bev);  // h2
      }
    }
  }
  __syncthreads();

  // ================= Phase 3: FFN (4 chunks of 384 over 1536) =================
  f32x4 facc[4][3];
#pragma unroll
  for (int m = 0; m < 4; ++m)
#pragma unroll
    for (int nl = 0; nl < 3; ++nl) facc[m][nl] = (f32x4){0.f, 0.f, 0.f, 0.f};
  const unsigned short* w2p = w2T + (size_t)(wv * 48 + l15) * 1536 + quad * 8;

#pragma unroll 1
  for (int c = 0; c < 4; ++c) {
    // FFN1: U^T = w1_chunk^T @ h2^T ; wave = (t-tile mt) x (12 cl-tiles)
    {
      f32x4 uacc[12];
#pragma unroll
      for (int j = 0; j < 12; ++j) uacc[j] = (f32x4){0.f, 0.f, 0.f, 0.f};
      const unsigned short* hp = sH + (mt * 16 + l15) * 392 + quad * 8;
      const unsigned short* w1p = w1T + (size_t)(c * 384 + grp * 192 + l15) * 384 + quad * 8;
#pragma unroll 2
      for (int k = 0; k < 12; ++k) {
        short8 hb = *(const short8*)(hp + k * 32);
#pragma unroll
        for (int j = 0; j < 12; ++j)
          uacc[j] = __builtin_amdgcn_mfma_f32_16x16x32_bf16(*(const short8*)(w1p + j * 6144 + k * 32), hb, uacc[j], 0, 0, 0);
      }
#pragma unroll
      for (int j = 0; j < 12; ++j) {
        int rb = c * 384 + grp * 192 + j * 16 + quad * 4;
        float4 b1v = *(const float4*)&b1[rb];
        float u0 = fmaxf(uacc[j][0] + b1v.x, 0.f);
        float u1 = fmaxf(uacc[j][1] + b1v.y, 0.f);
        float u2 = fmaxf(uacc[j][2] + b1v.z, 0.f);
        float u3 = fmaxf(uacc[j][3] + b1v.w, 0.f);
        *(uint2*)&sA[(mt * 16 + l15) * 392 + grp * 192 + j * 16 + quad * 4] =
            make_uint2(pk2(u0, u1), pk2(u2, u3));
      }
    }
    __syncthreads();
    // FFN2: wave owns 3 n-tiles, all 4 t-tiles
#pragma unroll 2
    for (int k = 0; k < 12; ++k) {
      short8 a[4];
#pragma unroll
      for (int m = 0; m < 4; ++m)
        a[m] = *(const short8*)&sA[(m * 16 + l15) * 392 + k * 32 + quad * 8];
#pragma unroll
      for (int nl = 0; nl < 3; ++nl) {
        short8 bb = *(const short8*)(w2p + nl * 24576 + c * 384 + k * 32);
#pragma unroll
        for (int m = 0; m < 4; ++m)
          facc[m][nl] = __builtin_amdgcn_mfma_f32_16x16x32_bf16(a[m], bb, facc[m][nl], 0, 0, 0);
      }
    }
    __syncthreads();
  }

  // ================= Epilogue: out = h2 + ff + b2 =================
#pragma unroll
  for (int nl = 0; nl < 3; ++nl) {
    int n = (wv * 3 + nl) * 16 + l15;
    float b2v = b2[n];
#pragma unroll
    for (int m = 0; m < 4; ++m) {
#pragma unroll
      for (int i = 0; i < 4; ++i) {
        int t = m * 16 + quad * 4 + i;
        out[((size_t)b * 64 + t) * 384 + n] = facc[m][nl][i] + b2v + bf2f(sH[t * 392 + n]);
      }
    }
  }
}

extern "C" void kernel_launch(void* const* d_in, const int* in_sizes, int n_in,
                              void* d_out, int out_size, void* d_ws, size_t ws_size,
                              hipStream_t stream) {
  const float* x   = (const float*)d_in[0];
  const float* wq  = (const float*)d_in[1];
  const float* bq  = (const float*)d_in[2];
  const float* wk  = (const float*)d_in[3];
  const float* bk  = (const float*)d_in[4];
  const float* wv  = (const float*)d_in[5];
  const float* bv  = (const float*)d_in[6];
  const float* wo  = (const float*)d_in[7];
  const float* bo  = (const float*)d_in[8];
  const float* w1  = (const float*)d_in[9];
  const float* b1  = (const float*)d_in[10];
  const float* w2  = (const float*)d_in[11];
  const float* b2  = (const float*)d_in[12];
  const float* g1  = (const float*)d_in[13];
  const float* be1 = (const float*)d_in[14];
  const float* g2  = (const float*)d_in[15];
  const float* be2 = (const float*)d_in[16];
  unsigned short* wt = (unsigned short*)d_ws;
  float* out = (float*)d_out;

  int nbatch = in_sizes[0] / (64 * 384);    // 2048
  prep_kernel<<<(1769472 + 255) / 256, 256, 0, stream>>>(wq, wk, wv, wo, w1, w2, wt);
  block_fused<<<nbatch, 512, 0, stream>>>(x, bq, bk, bv, bo, b1, b2,
                                          g1, be1, g2, be2, wt, out);
}